// Round 9
// baseline (81.685 us; speedup 1.0000x reference)
//
#include <hip/hip_runtime.h>

#define NB 4
#define NE 16
#define NHW (512*512)
#define NINST 32
#define DELTA_VAR 0.5f
#define DELTA_DIST 1.5f
#define ALPHA 1.0f
#define BETA 1.0f
#define GAMMA 0.001f

typedef __attribute__((ext_vector_type(8))) short short8;
typedef __attribute__((ext_vector_type(4))) float f32x4;

// ---- shared geometry: 1024 blocks x 256 thr (4 waves), 1024 px/block ----
#define GRID_B 1024
#define BLK 256
#define BPB 256                   // blocks per batch
#define PXB 1024                  // px per block
#define ELSTR 1036                // padded LDS row stride (floats): 16B-aligned,
                                  // bank shift 12e%32 -> 8 starts -> ~2-way
#define PH_STRIDE 544             // [32][16] sums + [32] counts

// ---- ws layout (floats); every slot written before read each call ----
#define P_HIST 0                             // [NB][PH_STRIDE][BPB] transposed partials
#define T_MEAN (GRID_B*PH_STRIDE)            // [NB][33*16], label 0 = zeros
#define T_MEAN_SZ (33*NE)
#define T_DIST (T_MEAN + NB*T_MEAN_SZ)
#define T_REG  (T_DIST + NB)
#define T_NS   (T_REG + NB)
#define VACC   (T_NS + NB)                   // [NB] var accumulators (atomic)
#define VCNT   (VACC + NB)                   // 1 x u32 completion counter

#define LMSTR 660                            // 33*20 floats per mean replica

__device__ __forceinline__ unsigned f2bf(float x) {
    unsigned u = __builtin_bit_cast(unsigned, x);
    return (u + 0x7FFFu + ((u >> 16) & 1u)) >> 16;   // RNE bf16
}

__device__ __forceinline__ float wave_sum(float v) {
    #pragma unroll
    for (int o = 32; o > 0; o >>= 1) v += __shfl_down(v, o, 64);
    return v;
}

// async global->LDS DMA, 16 B/lane, no VGPR destination -> compiler issues
// back-to-back with nothing in flight-limited by registers
__device__ __forceinline__ void gl16(const void* g, void* l) {
    __builtin_amdgcn_global_load_lds((const __attribute__((address_space(1))) void*)g,
                                     (__attribute__((address_space(3))) void*)l, 16, 0, 0);
}

union PK { unsigned u[4]; short8 s; };

__global__ __launch_bounds__(BLK) void k_hist(const float* __restrict__ emb,
        const int* __restrict__ lab, float* __restrict__ ws) {
    __shared__ __align__(16) float elds[NE*ELSTR];   // 66304 B
    __shared__ __align__(16) int   llds[PXB];        //  4096 B
    __shared__ float red[4][2*NE][17];               //  8704 B
    __shared__ float redc[4][2*NE];                  //   512 B
    const int t = threadIdx.x;
    const int lane = t & 63;
    const int wv = t >> 6;
    const int colg = lane >> 4;
    const int cm = lane & 15;
    const int b = blockIdx.x >> 8;
    const int blk = blockIdx.x & 255;
    const float* ebase = emb + (size_t)b*(NE*NHW);
    const int* lbase = lab + (size_t)b*NHW;
    const int px0 = blk*PXB;

    // stage 64 emb runs (e,q: 256 floats each) + 4 label runs, wave-strided.
    // LDS dest: wave-uniform base, linear 1024B run (never crosses row pad).
    for (int k = wv; k < 68; k += 4) {
        if (k < 64) {
            const int e = k >> 2, q = k & 3;
            gl16(ebase + (size_t)e*NHW + px0 + q*256 + lane*4, &elds[e*ELSTR + q*256]);
        } else {
            const int q = k - 64;
            gl16(lbase + px0 + q*256 + lane*4, &llds[q*256]);
        }
    }
    __syncthreads();   // drains each wave's vmcnt, then barrier -> LDS complete

    f32x4 acc_s0 = {0.f,0.f,0.f,0.f}, acc_s1 = {0.f,0.f,0.f,0.f};
    f32x4 acc_c0 = {0.f,0.f,0.f,0.f}, acc_c1 = {0.f,0.f,0.f,0.f};
    PK ones; ones.u[0]=ones.u[1]=ones.u[2]=ones.u[3]=0x3F803F80u;

    // wave wv consumes chunks [wv*8, wv*8+8), 32 px each, from LDS
    for (int c8 = 0; c8 < 8; ++c8) {
        const int pxc = (wv*8 + c8)*32 + colg*8;
        const float4 v0 = *(const float4*)&elds[cm*ELSTR + pxc];
        const float4 v1 = *(const float4*)&elds[cm*ELSTR + pxc + 4];
        const int4 L0 = *(const int4*)&llds[pxc];        // 16-lane broadcast
        const int4 L1 = *(const int4*)&llds[pxc + 4];
        PK bf;
        bf.u[0] = f2bf(v0.x) | (f2bf(v0.y) << 16);
        bf.u[1] = f2bf(v0.z) | (f2bf(v0.w) << 16);
        bf.u[2] = f2bf(v1.x) | (f2bf(v1.y) << 16);
        bf.u[3] = f2bf(v1.z) | (f2bf(v1.w) << 16);
        const int la[8] = {L0.x,L0.y,L0.z,L0.w,L1.x,L1.y,L1.z,L1.w};
        PK a0, a1;
        #pragma unroll
        for (int p = 0; p < 4; ++p) {
            const unsigned lo0 = (la[2*p]   == cm+1 ) ? 0x3F80u : 0u;
            const unsigned hi0 = (la[2*p+1] == cm+1 ) ? 0x3F80u : 0u;
            const unsigned lo1 = (la[2*p]   == cm+17) ? 0x3F80u : 0u;
            const unsigned hi1 = (la[2*p+1] == cm+17) ? 0x3F80u : 0u;
            a0.u[p] = lo0 | (hi0 << 16);
            a1.u[p] = lo1 | (hi1 << 16);
        }
        acc_s0 = __builtin_amdgcn_mfma_f32_16x16x32_bf16(a0.s, bf.s,   acc_s0, 0,0,0);
        acc_s1 = __builtin_amdgcn_mfma_f32_16x16x32_bf16(a1.s, bf.s,   acc_s1, 0,0,0);
        acc_c0 = __builtin_amdgcn_mfma_f32_16x16x32_bf16(a0.s, ones.s, acc_c0, 0,0,0);
        acc_c1 = __builtin_amdgcn_mfma_f32_16x16x32_bf16(a1.s, ones.s, acc_c1, 0,0,0);
    }
    // D layout: col = lane&15 (channel), row = colg*4 + r (seg within half)
    #pragma unroll
    for (int r = 0; r < 4; ++r) {
        red[wv][colg*4 + r][cm]      = acc_s0[r];
        red[wv][16 + colg*4 + r][cm] = acc_s1[r];
    }
    if (cm == 0) {
        #pragma unroll
        for (int r = 0; r < 4; ++r) {
            redc[wv][colg*4 + r]      = acc_c0[r];
            redc[wv][16 + colg*4 + r] = acc_c1[r];
        }
    }
    __syncthreads();
    // transposed partial store: [b][item][blk]
    float* dst = ws + P_HIST + (size_t)b*PH_STRIDE*BPB + blk;
    for (int i = t; i < PH_STRIDE; i += BLK) {
        float v;
        if (i < 512) {
            const int s = i >> 4, e = i & 15;
            v = red[0][s][e] + red[1][s][e] + red[2][s][e] + red[3][s][e];
        } else {
            const int s = i - 512;
            v = redc[0][s] + redc[1][s] + redc[2][s] + redc[3][s];
        }
        dst[(size_t)i*BPB] = v;
    }
}

__global__ void k_stats(float* __restrict__ ws) {
    const int b = blockIdx.x;
    const int t = threadIdx.x;
    __shared__ float lred[PH_STRIDE];
    __shared__ float lmean[NINST*17];
    __shared__ float lcnt[NINST];
    __shared__ int lpres[NINST];
    const float* ph = ws + P_HIST + (size_t)b*PH_STRIDE*BPB;
    for (int i = t; i < PH_STRIDE; i += 512) {
        const float4* r4 = (const float4*)(ph + (size_t)i*BPB);
        float4 s4 = {0.f,0.f,0.f,0.f};
        #pragma unroll 8
        for (int k = 0; k < BPB/4; k++) {
            const float4 v = r4[k];
            s4.x += v.x; s4.y += v.y; s4.z += v.z; s4.w += v.w;
        }
        lred[i] = s4.x + s4.y + s4.z + s4.w;
    }
    __syncthreads();
    if (t < NINST) {
        const float c = lred[512 + t];
        lcnt[t] = c;
        lpres[t] = (c > 0.f) ? 1 : 0;
    }
    if (t == 0) {
        ws[VACC + b] = 0.f;
        if (b == 0) ((unsigned*)ws)[VCNT] = 0u;
    }
    __syncthreads();
    for (int i = t; i < 512; i += 512) {
        const int s = i >> 4, e = i & 15;
        lmean[s*17 + e] = lred[i] / fmaxf(lcnt[s], 1.f);
    }
    __syncthreads();
    for (int i = t; i < 33*NE; i += 512) {
        const int l = i >> 4, e = i & 15;
        ws[T_MEAN + b*T_MEAN_SZ + i] = (l == 0) ? 0.f : lmean[(l-1)*17 + e];
    }
    if (t < 64) {
        const int lane = t;
        const int n = __popcll(__ballot((lane < NINST) ? (lpres[lane] != 0) : false));
        float dsum = 0.f;
        for (int idx = lane; idx < NINST*NINST; idx += 64) {
            const int i = idx >> 5, j = idx & 31;
            if (i < j && lpres[i] && lpres[j]) {
                float d2 = 0.f;
                #pragma unroll
                for (int e = 0; e < NE; e++) {
                    const float df = lmean[i*17+e] - lmean[j*17+e];
                    d2 += df*df;
                }
                dsum += fmaxf(2.f*DELTA_DIST - sqrtf(d2), 0.f);
            }
        }
        dsum = wave_sum(dsum);
        float rsum = 0.f;
        if (lane < NINST && lpres[lane]) {
            float s2 = 0.f;
            #pragma unroll
            for (int e = 0; e < NE; e++) { const float m = lmean[lane*17+e]; s2 += m*m; }
            rsum = sqrtf(s2);
        }
        rsum = wave_sum(rsum);
        if (lane == 0) {
            const float nf = (float)n;
            const float nsafe = fmaxf(nf, 1.f);
            ws[T_DIST+b] = (n > 1) ? dsum / fmaxf(nf*(nf-1.f)*0.5f, 1.f) : 0.f;
            ws[T_REG+b] = rsum / nsafe;
            ws[T_NS+b] = nsafe;
        }
    }
}

__global__ __launch_bounds__(BLK) void k_var(const float* __restrict__ emb,
        const int* __restrict__ lab, float* __restrict__ ws, float* __restrict__ out) {
    __shared__ __align__(16) float elds[NE*ELSTR];   // 66304 B
    __shared__ __align__(16) int   llds[PXB];        //  4096 B
    __shared__ __align__(16) float lm[4*LMSTR];      // 10560 B
    __shared__ float wred[4];
    const int t = threadIdx.x;
    const int lane = t & 63;
    const int wv = t >> 6;
    const int b = blockIdx.x >> 8;
    const int blk = blockIdx.x & 255;
    const float* ebase = emb + (size_t)b*(NE*NHW);
    const int* lbase = lab + (size_t)b*NHW;
    const int px0 = blk*PXB;

    // stage emb + labels via DMA (identical pattern to k_hist)
    for (int k = wv; k < 68; k += 4) {
        if (k < 64) {
            const int e = k >> 2, q = k & 3;
            gl16(ebase + (size_t)e*NHW + px0 + q*256 + lane*4, &elds[e*ELSTR + q*256]);
        } else {
            const int q = k - 64;
            gl16(lbase + px0 + q*256 + lane*4, &llds[q*256]);
        }
    }
    // 4 replicated mean tables [33][20] (overlaps the DMAs)
    const float* gmean = ws + T_MEAN + b*T_MEAN_SZ;
    for (int i = t; i < 33*NE; i += BLK) {
        const int l = i >> 4, e = i & 15;
        const float v = gmean[i];
        lm[0*LMSTR + l*20 + e] = v;
        lm[1*LMSTR + l*20 + e] = v;
        lm[2*LMSTR + l*20 + e] = v;
        lm[3*LMSTR + l*20 + e] = v;
    }
    __syncthreads();

    const int4 l4 = *(const int4*)&llds[t*4];
    const float* lmc = lm + ((t >> 4) & 3)*LMSTR;
    float d0=0.f, d1=0.f, d2=0.f, d3=0.f;
    #pragma unroll
    for (int c = 0; c < 4; ++c) {
        const float4 m0 = *(const float4*)&lmc[l4.x*20 + c*4];
        const float4 m1 = *(const float4*)&lmc[l4.y*20 + c*4];
        const float4 m2 = *(const float4*)&lmc[l4.z*20 + c*4];
        const float4 m3 = *(const float4*)&lmc[l4.w*20 + c*4];
        #pragma unroll
        for (int j = 0; j < 4; ++j) {
            const float4 v = *(const float4*)&elds[(c*4+j)*ELSTR + t*4];
            float df;
            df = v.x - ((const float*)&m0)[j]; d0 += df*df;
            df = v.y - ((const float*)&m1)[j]; d1 += df*df;
            df = v.z - ((const float*)&m2)[j]; d2 += df*df;
            df = v.w - ((const float*)&m3)[j]; d3 += df*df;
        }
    }
    float acc = 0.f;
    if (l4.x > 0) acc += fmaxf(sqrtf(d0) - DELTA_VAR, 0.f);
    if (l4.y > 0) acc += fmaxf(sqrtf(d1) - DELTA_VAR, 0.f);
    if (l4.z > 0) acc += fmaxf(sqrtf(d2) - DELTA_VAR, 0.f);
    if (l4.w > 0) acc += fmaxf(sqrtf(d3) - DELTA_VAR, 0.f);

    const float wsum = wave_sum(acc);
    if (lane == 0) wred[wv] = wsum;
    __syncthreads();
    if (t == 0) {
        atomicAdd(&ws[VACC + b], wred[0]+wred[1]+wred[2]+wred[3]);
        __threadfence();
        const unsigned old = atomicAdd((unsigned*)&ws[VCNT], 1u);
        if (old == GRID_B - 1) {
            float tot = 0.f;
            #pragma unroll
            for (int bb = 0; bb < NB; bb++) {
                const float v = atomicAdd(&ws[VACC + bb], 0.f);   // coherent read
                tot += ALPHA * (v / ws[T_NS+bb])
                     + BETA * ws[T_DIST+bb]
                     + GAMMA * ws[T_REG+bb];
            }
            out[0] = tot * (1.f/NB);
        }
    }
}

extern "C" void kernel_launch(void* const* d_in, const int* in_sizes, int n_in,
                              void* d_out, int out_size, void* d_ws, size_t ws_size,
                              hipStream_t stream) {
    const float* emb = (const float*)d_in[0];
    const int* lab = (const int*)d_in[1];
    float* out = (float*)d_out;
    float* ws = (float*)d_ws;

    k_hist<<<GRID_B, BLK, 0, stream>>>(emb, lab, ws);
    k_stats<<<NB, 512, 0, stream>>>(ws);
    k_var<<<GRID_B, BLK, 0, stream>>>(emb, lab, ws, out);
}

// Round 10
// 78.884 us; speedup vs baseline: 1.0355x; 1.0355x over previous
//
#include <hip/hip_runtime.h>

#define NB 4
#define NE 16
#define NHW (512*512)
#define NINST 32
#define DELTA_VAR 0.5f
#define DELTA_DIST 1.5f
#define ALPHA 1.0f
#define BETA 1.0f
#define GAMMA 0.001f

typedef __attribute__((ext_vector_type(8))) short short8;
typedef __attribute__((ext_vector_type(4))) float f32x4;

// ---- k_hist geometry (r4-measured-good ~10us): 512 blocks x 256 thr ----
#define GRID_H 512
#define BLK_H 256
#define BPB_H (GRID_H/NB)            // 128 blocks per batch
#define PXB_H (NHW/BPB_H)            // 2048 px per block
#define CHUNKS_H 16                  // 4 waves * 16 chunks * 32 px = 2048
#define PH_STRIDE 544                // [32][16] sums + [32] counts

// ---- k_var geometry: 1024 blocks x 256 thr, 4 px/thread, one-shot ----
#define GRID_V 1024
#define BLK_V 256

// ---- ws layout (floats); every slot written before read each call ----
#define P_HIST 0                             // [NB][PH_STRIDE][BPB_H] transposed partials
#define T_MEAN (GRID_H*PH_STRIDE)            // [NB][33*16], label 0 = zeros
#define T_MEAN_SZ (33*NE)
#define T_DIST (T_MEAN + NB*T_MEAN_SZ)
#define T_REG  (T_DIST + NB)
#define T_NS   (T_REG + NB)
#define VACC   (T_NS + NB)                   // [NB] var accumulators (atomic)
#define VCNT   (VACC + NB)                   // 1 x u32 completion counter

#define LMREP 4
#define LMSTR 660                            // 33*20 floats per replica (16B aligned)

__device__ __forceinline__ unsigned f2bf(float x) {
    unsigned u = __builtin_bit_cast(unsigned, x);
    return (u + 0x7FFFu + ((u >> 16) & 1u)) >> 16;   // RNE bf16
}

__device__ __forceinline__ float wave_sum(float v) {
    #pragma unroll
    for (int o = 32; o > 0; o >>= 1) v += __shfl_down(v, o, 64);
    return v;
}

union PK { unsigned u[4]; short8 s; };

__global__ __launch_bounds__(BLK_H) void k_hist(const float* __restrict__ emb,
        const int* __restrict__ lab, float* __restrict__ ws) {
    __shared__ float red[4][2*NE][17];
    __shared__ float redc[4][2*NE];
    const int t = threadIdx.x;
    const int lane = t & 63;
    const int wv = t >> 6;
    const int colg = lane >> 4;
    const int cm = lane & 15;
    const int b = blockIdx.x / BPB_H;
    const int blk = blockIdx.x % BPB_H;

    const float* ebase = emb + (size_t)b*(NE*NHW) + (size_t)cm*NHW;
    const int* lbase = lab + (size_t)b*NHW;

    f32x4 acc_s0 = {0.f,0.f,0.f,0.f}, acc_s1 = {0.f,0.f,0.f,0.f};
    f32x4 acc_c0 = {0.f,0.f,0.f,0.f}, acc_c1 = {0.f,0.f,0.f,0.f};
    PK ones; ones.u[0]=ones.u[1]=ones.u[2]=ones.u[3]=0x3F803F80u;

    const int base = blk*PXB_H + wv*(PXB_H/4);
    #pragma unroll 4
    for (int it = 0; it < CHUNKS_H; ++it) {
        const int ko = base + it*32 + colg*8;
        const float4 v0 = *(const float4*)(ebase + ko);
        const float4 v1 = *(const float4*)(ebase + ko + 4);
        const int4 L0 = *(const int4*)(lbase + ko);
        const int4 L1 = *(const int4*)(lbase + ko + 4);
        PK bf;
        bf.u[0] = f2bf(v0.x) | (f2bf(v0.y) << 16);
        bf.u[1] = f2bf(v0.z) | (f2bf(v0.w) << 16);
        bf.u[2] = f2bf(v1.x) | (f2bf(v1.y) << 16);
        bf.u[3] = f2bf(v1.z) | (f2bf(v1.w) << 16);
        const int la[8] = {L0.x,L0.y,L0.z,L0.w,L1.x,L1.y,L1.z,L1.w};
        PK a0, a1;
        #pragma unroll
        for (int p = 0; p < 4; ++p) {
            const unsigned lo0 = (la[2*p]   == cm+1 ) ? 0x3F80u : 0u;
            const unsigned hi0 = (la[2*p+1] == cm+1 ) ? 0x3F80u : 0u;
            const unsigned lo1 = (la[2*p]   == cm+17) ? 0x3F80u : 0u;
            const unsigned hi1 = (la[2*p+1] == cm+17) ? 0x3F80u : 0u;
            a0.u[p] = lo0 | (hi0 << 16);
            a1.u[p] = lo1 | (hi1 << 16);
        }
        acc_s0 = __builtin_amdgcn_mfma_f32_16x16x32_bf16(a0.s, bf.s,   acc_s0, 0,0,0);
        acc_s1 = __builtin_amdgcn_mfma_f32_16x16x32_bf16(a1.s, bf.s,   acc_s1, 0,0,0);
        acc_c0 = __builtin_amdgcn_mfma_f32_16x16x32_bf16(a0.s, ones.s, acc_c0, 0,0,0);
        acc_c1 = __builtin_amdgcn_mfma_f32_16x16x32_bf16(a1.s, ones.s, acc_c1, 0,0,0);
    }
    // D layout: col = lane&15 (channel), row = colg*4 + r (seg within half)
    #pragma unroll
    for (int r = 0; r < 4; ++r) {
        red[wv][colg*4 + r][cm]      = acc_s0[r];
        red[wv][16 + colg*4 + r][cm] = acc_s1[r];
    }
    if (cm == 0) {
        #pragma unroll
        for (int r = 0; r < 4; ++r) {
            redc[wv][colg*4 + r]      = acc_c0[r];
            redc[wv][16 + colg*4 + r] = acc_c1[r];
        }
    }
    __syncthreads();
    // transposed partial store: [b][item][blk]
    float* dst = ws + P_HIST + (size_t)b*PH_STRIDE*BPB_H + blk;
    for (int i = t; i < PH_STRIDE; i += BLK_H) {
        float v;
        if (i < 512) {
            const int s = i >> 4, e = i & 15;
            v = red[0][s][e] + red[1][s][e] + red[2][s][e] + red[3][s][e];
        } else {
            const int s = i - 512;
            v = redc[0][s] + redc[1][s] + redc[2][s] + redc[3][s];
        }
        dst[(size_t)i*BPB_H] = v;
    }
}

__global__ void k_stats(float* __restrict__ ws) {
    const int b = blockIdx.x;
    const int t = threadIdx.x;
    __shared__ float lred[PH_STRIDE];
    __shared__ float lmean[NINST*17];
    __shared__ float lcnt[NINST];
    __shared__ int lpres[NINST];
    const float* ph = ws + P_HIST + (size_t)b*PH_STRIDE*BPB_H;
    for (int i = t; i < PH_STRIDE; i += 256) {
        const float4* r4 = (const float4*)(ph + (size_t)i*BPB_H);
        float4 s4 = {0.f,0.f,0.f,0.f};
        #pragma unroll 8
        for (int k = 0; k < BPB_H/4; k++) {
            const float4 v = r4[k];
            s4.x += v.x; s4.y += v.y; s4.z += v.z; s4.w += v.w;
        }
        lred[i] = s4.x + s4.y + s4.z + s4.w;
    }
    __syncthreads();
    if (t < NINST) {
        const float c = lred[512 + t];
        lcnt[t] = c;
        lpres[t] = (c > 0.f) ? 1 : 0;
    }
    if (t == 0) {
        ws[VACC + b] = 0.f;
        if (b == 0) ((unsigned*)ws)[VCNT] = 0u;
    }
    __syncthreads();
    for (int i = t; i < 512; i += 256) {
        const int s = i >> 4, e = i & 15;
        lmean[s*17 + e] = lred[i] / fmaxf(lcnt[s], 1.f);
    }
    __syncthreads();
    for (int i = t; i < 33*NE; i += 256) {
        const int l = i >> 4, e = i & 15;
        ws[T_MEAN + b*T_MEAN_SZ + i] = (l == 0) ? 0.f : lmean[(l-1)*17 + e];
    }
    if (t < 64) {
        const int lane = t;
        const int n = __popcll(__ballot((lane < NINST) ? (lpres[lane] != 0) : false));
        float dsum = 0.f;
        for (int idx = lane; idx < NINST*NINST; idx += 64) {
            const int i = idx >> 5, j = idx & 31;
            if (i < j && lpres[i] && lpres[j]) {
                float d2 = 0.f;
                #pragma unroll
                for (int e = 0; e < NE; e++) {
                    const float df = lmean[i*17+e] - lmean[j*17+e];
                    d2 += df*df;
                }
                dsum += fmaxf(2.f*DELTA_DIST - sqrtf(d2), 0.f);
            }
        }
        dsum = wave_sum(dsum);
        float rsum = 0.f;
        if (lane < NINST && lpres[lane]) {
            float s2 = 0.f;
            #pragma unroll
            for (int e = 0; e < NE; e++) { const float m = lmean[lane*17+e]; s2 += m*m; }
            rsum = sqrtf(s2);
        }
        rsum = wave_sum(rsum);
        if (lane == 0) {
            const float nf = (float)n;
            const float nsafe = fmaxf(nf, 1.f);
            ws[T_DIST+b] = (n > 1) ? dsum / fmaxf(nf*(nf-1.f)*0.5f, 1.f) : 0.f;
            ws[T_REG+b] = rsum / nsafe;
            ws[T_NS+b] = nsafe;
        }
    }
}

// r4 k_var + the missing lever: __launch_bounds__(256,1) lifts the VGPR cap
// (default heuristic chose 56 regs -> ev[16] spilled to scratch -> loads
// serialized by spill vmcnt chains, 41us latency-bound). With min-waves=1 the
// allocator can hold all 17 loads' results live: 17 KB in flight per wave,
// ~16 waves/CU -> BW-bound.
__global__ __launch_bounds__(BLK_V, 1) void k_var(const float* __restrict__ emb,
        const int* __restrict__ lab, float* __restrict__ ws, float* __restrict__ out) {
    __shared__ __align__(16) float lm[LMREP*LMSTR];
    __shared__ float wred[4];
    const int t = threadIdx.x;
    const int b = blockIdx.x >> 8;
    const int blk = blockIdx.x & 255;
    const float* ebase = emb + (size_t)b*(NE*NHW);
    const int* lbase = lab + (size_t)b*NHW;
    const int p = (blk*BLK_V + t)*4;

    // prefetch labels + all emb channels; barrier below forces vmcnt(0) drain
    // with all 17 loads simultaneously in flight (max MLP)
    const int4 l4 = *(const int4*)(lbase + p);
    float4 ev[NE];
    #pragma unroll
    for (int e = 0; e < NE; e++) ev[e] = *(const float4*)(ebase + (size_t)e*NHW + p);

    // 4 replicated mean tables, [33][20] each
    for (int i = t; i < 33*NE; i += BLK_V) {
        const int l = i >> 4, e = i & 15;
        const float v = ws[T_MEAN + b*T_MEAN_SZ + i];
        #pragma unroll
        for (int r = 0; r < LMREP; r++) lm[r*LMSTR + l*20 + e] = v;
    }
    __syncthreads();

    const float* lmc = lm + ((t >> 4) & (LMREP-1))*LMSTR;
    const float4* q0 = (const float4*)(lmc + l4.x*20);
    const float4* q1 = (const float4*)(lmc + l4.y*20);
    const float4* q2 = (const float4*)(lmc + l4.z*20);
    const float4* q3 = (const float4*)(lmc + l4.w*20);
    float d0=0.f, d1=0.f, d2=0.f, d3=0.f;
    #pragma unroll
    for (int c = 0; c < 4; c++) {
        const float4 ma = q0[c];
        const float4 mb = q1[c];
        const float4 mc_ = q2[c];
        const float4 md = q3[c];
        #pragma unroll
        for (int j = 0; j < 4; j++) {
            const float4 v = ev[4*c + j];
            float df;
            df = v.x - ((const float*)&ma)[j];  d0 += df*df;
            df = v.y - ((const float*)&mb)[j];  d1 += df*df;
            df = v.z - ((const float*)&mc_)[j]; d2 += df*df;
            df = v.w - ((const float*)&md)[j];  d3 += df*df;
        }
    }
    float acc = 0.f;
    if (l4.x > 0) acc += fmaxf(sqrtf(d0) - DELTA_VAR, 0.f);
    if (l4.y > 0) acc += fmaxf(sqrtf(d1) - DELTA_VAR, 0.f);
    if (l4.z > 0) acc += fmaxf(sqrtf(d2) - DELTA_VAR, 0.f);
    if (l4.w > 0) acc += fmaxf(sqrtf(d3) - DELTA_VAR, 0.f);

    const float wsum = wave_sum(acc);
    if ((t & 63) == 0) wred[t >> 6] = wsum;
    __syncthreads();
    if (t == 0) {
        atomicAdd(&ws[VACC + b], wred[0]+wred[1]+wred[2]+wred[3]);
        __threadfence();
        const unsigned old = atomicAdd((unsigned*)&ws[VCNT], 1u);
        if (old == GRID_V - 1) {
            float tot = 0.f;
            #pragma unroll
            for (int bb = 0; bb < NB; bb++) {
                const float v = atomicAdd(&ws[VACC + bb], 0.f);   // coherent read
                tot += ALPHA * (v / ws[T_NS+bb])
                     + BETA * ws[T_DIST+bb]
                     + GAMMA * ws[T_REG+bb];
            }
            out[0] = tot * (1.f/NB);
        }
    }
}

extern "C" void kernel_launch(void* const* d_in, const int* in_sizes, int n_in,
                              void* d_out, int out_size, void* d_ws, size_t ws_size,
                              hipStream_t stream) {
    const float* emb = (const float*)d_in[0];
    const int* lab = (const int*)d_in[1];
    float* out = (float*)d_out;
    float* ws = (float*)d_ws;

    k_hist<<<GRID_H, BLK_H, 0, stream>>>(emb, lab, ws);
    k_stats<<<NB, 256, 0, stream>>>(ws);
    k_var<<<GRID_V, BLK_V, 0, stream>>>(emb, lab, ws, out);
}

// Round 11
// 75.007 us; speedup vs baseline: 1.0890x; 1.0517x over previous
//
#include <hip/hip_runtime.h>

#define NB 4
#define NE 16
#define NHW (512*512)
#define NINST 32
#define DELTA_VAR 0.5f
#define DELTA_DIST 1.5f
#define ALPHA 1.0f
#define BETA 1.0f
#define GAMMA 0.001f

typedef __attribute__((ext_vector_type(8))) short short8;
typedef __attribute__((ext_vector_type(4))) float f32x4;

// ---- k_hist geometry: 1024 blocks x 256 thr (4 waves), 8 chunks/wave ----
// (P3 structure; only change vs the 53.5us round: 256x512 -> 1024x256 so
//  4 blocks/CU instead of 1 -> 16 waves/CU for latency hiding)
#define GRID_H 1024
#define BLK_H 256
#define BPB_H (GRID_H/NB)            // 256 blocks per batch
#define PXB_H (NHW/BPB_H)            // 1024 px per block
#define PXW_H 256                    // px per wave
#define CHUNKS_H 8                   // 8 chunks x 32 px = 256 px per wave
#define PH_STRIDE 544                // [32][16] sums + [32] counts

// ---- k_var geometry (P3-measured-good ~17us): 1024 x 256, one-shot ----
#define GRID_V 1024
#define BLK_V 256

// ---- ws layout (floats); every slot written before read each call ----
#define P_HIST 0                             // [GRID_H][PH_STRIDE] contiguous per block
#define T_MEAN (GRID_H*PH_STRIDE)            // [NB][33*16], label 0 = zeros
#define T_MEAN_SZ (33*NE)
#define T_DIST (T_MEAN + NB*T_MEAN_SZ)
#define T_REG  (T_DIST + NB)
#define T_NS   (T_REG + NB)
#define V_PART (T_NS + NB)                   // [1024] per-block var partials

#define LMREP 4
#define LMSTR 660                            // 33*20 floats per replica

__device__ __forceinline__ unsigned f2bf(float x) {
    unsigned u = __builtin_bit_cast(unsigned, x);
    return (u + 0x7FFFu + ((u >> 16) & 1u)) >> 16;   // RNE bf16
}

__device__ __forceinline__ float wave_sum(float v) {
    #pragma unroll
    for (int o = 32; o > 0; o >>= 1) v += __shfl_down(v, o, 64);
    return v;
}

union PK { unsigned u[4]; short8 s; };

__global__ __launch_bounds__(BLK_H) void k_hist(const float* __restrict__ emb,
        const int* __restrict__ lab, float* __restrict__ ws) {
    __shared__ float red[4][2*NE][17];
    __shared__ float redc[4][2*NE];
    const int t = threadIdx.x;
    const int lane = t & 63;
    const int wv = t >> 6;
    const int colg = lane >> 4;
    const int cm = lane & 15;
    const int b = blockIdx.x >> 8;
    const int blk = blockIdx.x & 255;

    const float* ebase = emb + (size_t)b*(NE*NHW) + (size_t)cm*NHW;
    const int* lbase = lab + (size_t)b*NHW;

    f32x4 acc_s0 = {0.f,0.f,0.f,0.f}, acc_s1 = {0.f,0.f,0.f,0.f};
    f32x4 acc_c0 = {0.f,0.f,0.f,0.f}, acc_c1 = {0.f,0.f,0.f,0.f};
    PK ones; ones.u[0]=ones.u[1]=ones.u[2]=ones.u[3]=0x3F803F80u;

    const int base = blk*PXB_H + wv*PXW_H;
    #pragma unroll 4
    for (int it = 0; it < CHUNKS_H; ++it) {
        const int ko = base + it*32 + colg*8;
        const float4 v0 = *(const float4*)(ebase + ko);
        const float4 v1 = *(const float4*)(ebase + ko + 4);
        const int4 L0 = *(const int4*)(lbase + ko);
        const int4 L1 = *(const int4*)(lbase + ko + 4);
        PK bf;
        bf.u[0] = f2bf(v0.x) | (f2bf(v0.y) << 16);
        bf.u[1] = f2bf(v0.z) | (f2bf(v0.w) << 16);
        bf.u[2] = f2bf(v1.x) | (f2bf(v1.y) << 16);
        bf.u[3] = f2bf(v1.z) | (f2bf(v1.w) << 16);
        const int la[8] = {L0.x,L0.y,L0.z,L0.w,L1.x,L1.y,L1.z,L1.w};
        PK a0, a1;
        #pragma unroll
        for (int p = 0; p < 4; ++p) {
            const unsigned lo0 = (la[2*p]   == cm+1 ) ? 0x3F80u : 0u;
            const unsigned hi0 = (la[2*p+1] == cm+1 ) ? 0x3F80u : 0u;
            const unsigned lo1 = (la[2*p]   == cm+17) ? 0x3F80u : 0u;
            const unsigned hi1 = (la[2*p+1] == cm+17) ? 0x3F80u : 0u;
            a0.u[p] = lo0 | (hi0 << 16);
            a1.u[p] = lo1 | (hi1 << 16);
        }
        acc_s0 = __builtin_amdgcn_mfma_f32_16x16x32_bf16(a0.s, bf.s,   acc_s0, 0,0,0);
        acc_s1 = __builtin_amdgcn_mfma_f32_16x16x32_bf16(a1.s, bf.s,   acc_s1, 0,0,0);
        acc_c0 = __builtin_amdgcn_mfma_f32_16x16x32_bf16(a0.s, ones.s, acc_c0, 0,0,0);
        acc_c1 = __builtin_amdgcn_mfma_f32_16x16x32_bf16(a1.s, ones.s, acc_c1, 0,0,0);
    }
    // D layout: col = lane&15 (channel), row = colg*4 + r (seg within half)
    #pragma unroll
    for (int r = 0; r < 4; ++r) {
        red[wv][colg*4 + r][cm]      = acc_s0[r];
        red[wv][16 + colg*4 + r][cm] = acc_s1[r];
    }
    if (cm == 0) {
        #pragma unroll
        for (int r = 0; r < 4; ++r) {
            redc[wv][colg*4 + r]      = acc_c0[r];
            redc[wv][16 + colg*4 + r] = acc_c1[r];
        }
    }
    __syncthreads();
    // contiguous per-block partial store: [blockIdx][item]
    float* dst = ws + P_HIST + (size_t)blockIdx.x*PH_STRIDE;
    for (int i = t; i < PH_STRIDE; i += BLK_H) {
        float v;
        if (i < 512) {
            const int s = i >> 4, e = i & 15;
            v = red[0][s][e] + red[1][s][e] + red[2][s][e] + red[3][s][e];
        } else {
            const int s = i - 512;
            v = redc[0][s] + redc[1][s] + redc[2][s] + redc[3][s];
        }
        dst[i] = v;
    }
}

__global__ void k_stats(float* __restrict__ ws) {
    const int b = blockIdx.x;
    const int t = threadIdx.x;
    __shared__ float lred[PH_STRIDE];
    __shared__ float lmean[NINST*17];
    __shared__ float lcnt[NINST];
    __shared__ int lpres[NINST];
    const float* ph = ws + P_HIST + (size_t)(b*BPB_H)*PH_STRIDE;
    for (int i = t; i < PH_STRIDE; i += 256) {
        float s = 0.f;
        #pragma unroll 8
        for (int k = 0; k < BPB_H; k++) s += ph[(size_t)k*PH_STRIDE + i];
        lred[i] = s;
    }
    __syncthreads();
    if (t < NINST) {
        const float c = lred[512 + t];
        lcnt[t] = c;
        lpres[t] = (c > 0.f) ? 1 : 0;
    }
    __syncthreads();
    for (int i = t; i < 512; i += 256) {
        const int s = i >> 4, e = i & 15;
        lmean[s*17 + e] = lred[i] / fmaxf(lcnt[s], 1.f);
    }
    __syncthreads();
    for (int i = t; i < 33*NE; i += 256) {
        const int l = i >> 4, e = i & 15;
        ws[T_MEAN + b*T_MEAN_SZ + i] = (l == 0) ? 0.f : lmean[(l-1)*17 + e];
    }
    if (t < 64) {
        const int lane = t;
        const int n = __popcll(__ballot((lane < NINST) ? (lpres[lane] != 0) : false));
        float dsum = 0.f;
        for (int idx = lane; idx < NINST*NINST; idx += 64) {
            const int i = idx >> 5, j = idx & 31;
            if (i < j && lpres[i] && lpres[j]) {
                float d2 = 0.f;
                #pragma unroll
                for (int e = 0; e < NE; e++) {
                    const float df = lmean[i*17+e] - lmean[j*17+e];
                    d2 += df*df;
                }
                dsum += fmaxf(2.f*DELTA_DIST - sqrtf(d2), 0.f);
            }
        }
        dsum = wave_sum(dsum);
        float rsum = 0.f;
        if (lane < NINST && lpres[lane]) {
            float s2 = 0.f;
            #pragma unroll
            for (int e = 0; e < NE; e++) { const float m = lmean[lane*17+e]; s2 += m*m; }
            rsum = sqrtf(s2);
        }
        rsum = wave_sum(rsum);
        if (lane == 0) {
            const float nf = (float)n;
            const float nsafe = fmaxf(nf, 1.f);
            ws[T_DIST+b] = (n > 1) ? dsum / fmaxf(nf*(nf-1.f)*0.5f, 1.f) : 0.f;
            ws[T_REG+b] = rsum / nsafe;
            ws[T_NS+b] = nsafe;
        }
    }
}

// P3-measured-good k_var (~17us): LDS mean fill + barrier FIRST, then LDS
// gather into m-regs, then 16 streaming emb loads feeding independent FMA
// chains — compiler pipelines the loads, no big live array across a barrier.
__global__ __launch_bounds__(BLK_V) void k_var(const float* __restrict__ emb,
        const int* __restrict__ lab, float* __restrict__ ws) {
    __shared__ __align__(16) float lm[LMREP*LMSTR];
    __shared__ float wred[4];
    const int t = threadIdx.x;
    const int b = blockIdx.x >> 8;
    const int blk = blockIdx.x & 255;
    // fill 4 replicated mean tables, [33][20] each (cols 16..19 unused)
    for (int c4 = 0; c4 < LMREP; ++c4) {
        for (int i = t; i < 33*20; i += BLK_V) {
            const int l = i / 20, e = i % 20;
            if (e < 16) lm[c4*LMSTR + i] = ws[T_MEAN + b*T_MEAN_SZ + l*16 + e];
        }
    }
    __syncthreads();
    const float* lmc = lm + ((t >> 4) & (LMREP-1))*LMSTR;
    const float* ebase = emb + (size_t)b*(NE*NHW);
    const int* lbase = lab + (size_t)b*NHW;

    const int p = (blk*BLK_V + t)*4;
    const int4 l4 = *(const int4*)(lbase + p);
    float4 m0[4], m1[4], m2[4], m3[4];
    {
        const float4* q0 = (const float4*)(lmc + l4.x*20);
        const float4* q1 = (const float4*)(lmc + l4.y*20);
        const float4* q2 = (const float4*)(lmc + l4.z*20);
        const float4* q3 = (const float4*)(lmc + l4.w*20);
        #pragma unroll
        for (int c = 0; c < 4; ++c) { m0[c]=q0[c]; m1[c]=q1[c]; m2[c]=q2[c]; m3[c]=q3[c]; }
    }
    float d0=0.f, d1=0.f, d2=0.f, d3=0.f;
    #pragma unroll
    for (int e = 0; e < NE; e++) {
        const float4 v = *(const float4*)(ebase + (size_t)e*NHW + p);
        float df;
        df = v.x - ((const float*)&m0[e>>2])[e&3]; d0 += df*df;
        df = v.y - ((const float*)&m1[e>>2])[e&3]; d1 += df*df;
        df = v.z - ((const float*)&m2[e>>2])[e&3]; d2 += df*df;
        df = v.w - ((const float*)&m3[e>>2])[e&3]; d3 += df*df;
    }
    float acc = 0.f;
    if (l4.x > 0) acc += fmaxf(sqrtf(d0) - DELTA_VAR, 0.f);
    if (l4.y > 0) acc += fmaxf(sqrtf(d1) - DELTA_VAR, 0.f);
    if (l4.z > 0) acc += fmaxf(sqrtf(d2) - DELTA_VAR, 0.f);
    if (l4.w > 0) acc += fmaxf(sqrtf(d3) - DELTA_VAR, 0.f);

    const float wsum = wave_sum(acc);
    if ((t & 63) == 0) wred[t >> 6] = wsum;
    __syncthreads();
    if (t == 0) ws[V_PART + blockIdx.x] = wred[0]+wred[1]+wred[2]+wred[3];
}

__global__ void k_final(const float* __restrict__ ws, float* __restrict__ out) {
    const int t = threadIdx.x;              // 256 thr; wave w <-> batch w
    __shared__ float vb[4];
    float s = 0.f;
    #pragma unroll
    for (int k = 0; k < 4; ++k) s += ws[V_PART + t*4 + k];
    s = wave_sum(s);
    if ((t & 63) == 0) vb[t >> 6] = s;
    __syncthreads();
    if (t == 0) {
        float tot = 0.f;
        for (int b = 0; b < NB; b++) {
            tot += ALPHA * (vb[b] / ws[T_NS+b])
                 + BETA * ws[T_DIST+b]
                 + GAMMA * ws[T_REG+b];
        }
        out[0] = tot * (1.f/NB);
    }
}

extern "C" void kernel_launch(void* const* d_in, const int* in_sizes, int n_in,
                              void* d_out, int out_size, void* d_ws, size_t ws_size,
                              hipStream_t stream) {
    const float* emb = (const float*)d_in[0];
    const int* lab = (const int*)d_in[1];
    float* out = (float*)d_out;
    float* ws = (float*)d_ws;

    k_hist<<<GRID_H, BLK_H, 0, stream>>>(emb, lab, ws);
    k_stats<<<NB, 256, 0, stream>>>(ws);
    k_var<<<GRID_V, BLK_V, 0, stream>>>(emb, lab, ws);
    k_final<<<1, 256, 0, stream>>>(ws, out);
}

// Round 12
// 63.441 us; speedup vs baseline: 1.2876x; 1.1823x over previous
//
#include <hip/hip_runtime.h>

#define NB 4
#define NE 16
#define NHW (512*512)
#define NINST 32
#define DELTA_VAR 0.5f
#define DELTA_DIST 1.5f
#define ALPHA 1.0f
#define BETA 1.0f
#define GAMMA 0.001f

typedef __attribute__((ext_vector_type(8))) short short8;
typedef __attribute__((ext_vector_type(4))) float f32x4;

// ---- k_hist geometry (r11-measured ~13us): 1024 blocks x 256 thr ----
#define GRID_H 1024
#define BLK_H 256
#define BPB_H (GRID_H/NB)            // 256 blocks per batch
#define PXB_H (NHW/BPB_H)            // 1024 px per block
#define PXW_H 256                    // px per wave
#define CHUNKS_H 8                   // 8 chunks x 32 px = 256 px per wave
#define PH_STRIDE 544                // [32][16] sums + [32] counts

// ---- k_var geometry (P3/r11-measured ~15us): 1024 x 256, one-shot ----
#define GRID_V 1024
#define BLK_V 256

// ---- ws layout (floats); every slot written before read each call ----
#define P_HIST 0                             // [NB][PH_STRIDE][BPB_H] TRANSPOSED partials
#define T_MEAN (GRID_H*PH_STRIDE)            // [NB][33*16], label 0 = zeros
#define T_MEAN_SZ (33*NE)
#define T_DIST (T_MEAN + NB*T_MEAN_SZ)
#define T_REG  (T_DIST + NB)
#define T_NS   (T_REG + NB)
#define V_PART (T_NS + NB)                   // [1024] per-block var partials

#define LMREP 4
#define LMSTR 660                            // 33*20 floats per replica

__device__ __forceinline__ unsigned f2bf(float x) {
    unsigned u = __builtin_bit_cast(unsigned, x);
    return (u + 0x7FFFu + ((u >> 16) & 1u)) >> 16;   // RNE bf16
}

__device__ __forceinline__ float wave_sum(float v) {
    #pragma unroll
    for (int o = 32; o > 0; o >>= 1) v += __shfl_down(v, o, 64);
    return v;
}

union PK { unsigned u[4]; short8 s; };

__global__ __launch_bounds__(BLK_H) void k_hist(const float* __restrict__ emb,
        const int* __restrict__ lab, float* __restrict__ ws) {
    __shared__ float red[4][2*NE][17];
    __shared__ float redc[4][2*NE];
    const int t = threadIdx.x;
    const int lane = t & 63;
    const int wv = t >> 6;
    const int colg = lane >> 4;
    const int cm = lane & 15;
    const int b = blockIdx.x >> 8;
    const int blk = blockIdx.x & 255;

    const float* ebase = emb + (size_t)b*(NE*NHW) + (size_t)cm*NHW;
    const int* lbase = lab + (size_t)b*NHW;

    f32x4 acc_s0 = {0.f,0.f,0.f,0.f}, acc_s1 = {0.f,0.f,0.f,0.f};
    f32x4 acc_c0 = {0.f,0.f,0.f,0.f}, acc_c1 = {0.f,0.f,0.f,0.f};
    PK ones; ones.u[0]=ones.u[1]=ones.u[2]=ones.u[3]=0x3F803F80u;

    const int base = blk*PXB_H + wv*PXW_H;
    #pragma unroll 4
    for (int it = 0; it < CHUNKS_H; ++it) {
        const int ko = base + it*32 + colg*8;
        const float4 v0 = *(const float4*)(ebase + ko);
        const float4 v1 = *(const float4*)(ebase + ko + 4);
        const int4 L0 = *(const int4*)(lbase + ko);
        const int4 L1 = *(const int4*)(lbase + ko + 4);
        PK bf;
        bf.u[0] = f2bf(v0.x) | (f2bf(v0.y) << 16);
        bf.u[1] = f2bf(v0.z) | (f2bf(v0.w) << 16);
        bf.u[2] = f2bf(v1.x) | (f2bf(v1.y) << 16);
        bf.u[3] = f2bf(v1.z) | (f2bf(v1.w) << 16);
        const int la[8] = {L0.x,L0.y,L0.z,L0.w,L1.x,L1.y,L1.z,L1.w};
        PK a0, a1;
        #pragma unroll
        for (int p = 0; p < 4; ++p) {
            const unsigned lo0 = (la[2*p]   == cm+1 ) ? 0x3F80u : 0u;
            const unsigned hi0 = (la[2*p+1] == cm+1 ) ? 0x3F80u : 0u;
            const unsigned lo1 = (la[2*p]   == cm+17) ? 0x3F80u : 0u;
            const unsigned hi1 = (la[2*p+1] == cm+17) ? 0x3F80u : 0u;
            a0.u[p] = lo0 | (hi0 << 16);
            a1.u[p] = lo1 | (hi1 << 16);
        }
        acc_s0 = __builtin_amdgcn_mfma_f32_16x16x32_bf16(a0.s, bf.s,   acc_s0, 0,0,0);
        acc_s1 = __builtin_amdgcn_mfma_f32_16x16x32_bf16(a1.s, bf.s,   acc_s1, 0,0,0);
        acc_c0 = __builtin_amdgcn_mfma_f32_16x16x32_bf16(a0.s, ones.s, acc_c0, 0,0,0);
        acc_c1 = __builtin_amdgcn_mfma_f32_16x16x32_bf16(a1.s, ones.s, acc_c1, 0,0,0);
    }
    // D layout: col = lane&15 (channel), row = colg*4 + r (seg within half)
    #pragma unroll
    for (int r = 0; r < 4; ++r) {
        red[wv][colg*4 + r][cm]      = acc_s0[r];
        red[wv][16 + colg*4 + r][cm] = acc_s1[r];
    }
    if (cm == 0) {
        #pragma unroll
        for (int r = 0; r < 4; ++r) {
            redc[wv][colg*4 + r]      = acc_c0[r];
            redc[wv][16 + colg*4 + r] = acc_c1[r];
        }
    }
    __syncthreads();
    // TRANSPOSED partial store: [b][item][blk] -> k_stats reads contiguous runs
    float* dst = ws + P_HIST + (size_t)b*PH_STRIDE*BPB_H + blk;
    for (int i = t; i < PH_STRIDE; i += BLK_H) {
        float v;
        if (i < 512) {
            const int s = i >> 4, e = i & 15;
            v = red[0][s][e] + red[1][s][e] + red[2][s][e] + red[3][s][e];
        } else {
            const int s = i - 512;
            v = redc[0][s] + redc[1][s] + redc[2][s] + redc[3][s];
        }
        dst[(size_t)i*BPB_H] = v;
    }
}

__global__ void k_stats(float* __restrict__ ws) {
    const int b = blockIdx.x;
    const int t = threadIdx.x;
    __shared__ float lred[PH_STRIDE];
    __shared__ float lmean[NINST*17];
    __shared__ float lcnt[NINST];
    __shared__ int lpres[NINST];
    const float* ph = ws + P_HIST + (size_t)b*PH_STRIDE*BPB_H;
    // each item's 256 partials are contiguous: 64 x float4, unroll 8 for MLP
    for (int i = t; i < PH_STRIDE; i += 256) {
        const float4* r4 = (const float4*)(ph + (size_t)i*BPB_H);
        float4 s4 = {0.f,0.f,0.f,0.f};
        #pragma unroll 8
        for (int k = 0; k < BPB_H/4; k++) {
            const float4 v = r4[k];
            s4.x += v.x; s4.y += v.y; s4.z += v.z; s4.w += v.w;
        }
        lred[i] = s4.x + s4.y + s4.z + s4.w;
    }
    __syncthreads();
    if (t < NINST) {
        const float c = lred[512 + t];
        lcnt[t] = c;
        lpres[t] = (c > 0.f) ? 1 : 0;
    }
    __syncthreads();
    for (int i = t; i < 512; i += 256) {
        const int s = i >> 4, e = i & 15;
        lmean[s*17 + e] = lred[i] / fmaxf(lcnt[s], 1.f);
    }
    __syncthreads();
    for (int i = t; i < 33*NE; i += 256) {
        const int l = i >> 4, e = i & 15;
        ws[T_MEAN + b*T_MEAN_SZ + i] = (l == 0) ? 0.f : lmean[(l-1)*17 + e];
    }
    if (t < 64) {
        const int lane = t;
        const int n = __popcll(__ballot((lane < NINST) ? (lpres[lane] != 0) : false));
        float dsum = 0.f;
        for (int idx = lane; idx < NINST*NINST; idx += 64) {
            const int i = idx >> 5, j = idx & 31;
            if (i < j && lpres[i] && lpres[j]) {
                float d2 = 0.f;
                #pragma unroll
                for (int e = 0; e < NE; e++) {
                    const float df = lmean[i*17+e] - lmean[j*17+e];
                    d2 += df*df;
                }
                dsum += fmaxf(2.f*DELTA_DIST - sqrtf(d2), 0.f);
            }
        }
        dsum = wave_sum(dsum);
        float rsum = 0.f;
        if (lane < NINST && lpres[lane]) {
            float s2 = 0.f;
            #pragma unroll
            for (int e = 0; e < NE; e++) { const float m = lmean[lane*17+e]; s2 += m*m; }
            rsum = sqrtf(s2);
        }
        rsum = wave_sum(rsum);
        if (lane == 0) {
            const float nf = (float)n;
            const float nsafe = fmaxf(nf, 1.f);
            ws[T_DIST+b] = (n > 1) ? dsum / fmaxf(nf*(nf-1.f)*0.5f, 1.f) : 0.f;
            ws[T_REG+b] = rsum / nsafe;
            ws[T_NS+b] = nsafe;
        }
    }
}

// P3/r11-measured-good k_var: LDS mean fill + barrier FIRST, then LDS gather
// into m-regs, then 16 streaming emb loads feeding independent FMA chains.
__global__ __launch_bounds__(BLK_V) void k_var(const float* __restrict__ emb,
        const int* __restrict__ lab, float* __restrict__ ws) {
    __shared__ __align__(16) float lm[LMREP*LMSTR];
    __shared__ float wred[4];
    const int t = threadIdx.x;
    const int b = blockIdx.x >> 8;
    const int blk = blockIdx.x & 255;
    // fill 4 replicated mean tables, [33][20] each (cols 16..19 unused)
    for (int c4 = 0; c4 < LMREP; ++c4) {
        for (int i = t; i < 33*20; i += BLK_V) {
            const int l = i / 20, e = i % 20;
            if (e < 16) lm[c4*LMSTR + i] = ws[T_MEAN + b*T_MEAN_SZ + l*16 + e];
        }
    }
    __syncthreads();
    const float* lmc = lm + ((t >> 4) & (LMREP-1))*LMSTR;
    const float* ebase = emb + (size_t)b*(NE*NHW);
    const int* lbase = lab + (size_t)b*NHW;

    const int p = (blk*BLK_V + t)*4;
    const int4 l4 = *(const int4*)(lbase + p);
    float4 m0[4], m1[4], m2[4], m3[4];
    {
        const float4* q0 = (const float4*)(lmc + l4.x*20);
        const float4* q1 = (const float4*)(lmc + l4.y*20);
        const float4* q2 = (const float4*)(lmc + l4.z*20);
        const float4* q3 = (const float4*)(lmc + l4.w*20);
        #pragma unroll
        for (int c = 0; c < 4; ++c) { m0[c]=q0[c]; m1[c]=q1[c]; m2[c]=q2[c]; m3[c]=q3[c]; }
    }
    float d0=0.f, d1=0.f, d2=0.f, d3=0.f;
    #pragma unroll
    for (int e = 0; e < NE; e++) {
        const float4 v = *(const float4*)(ebase + (size_t)e*NHW + p);
        float df;
        df = v.x - ((const float*)&m0[e>>2])[e&3]; d0 += df*df;
        df = v.y - ((const float*)&m1[e>>2])[e&3]; d1 += df*df;
        df = v.z - ((const float*)&m2[e>>2])[e&3]; d2 += df*df;
        df = v.w - ((const float*)&m3[e>>2])[e&3]; d3 += df*df;
    }
    float acc = 0.f;
    if (l4.x > 0) acc += fmaxf(sqrtf(d0) - DELTA_VAR, 0.f);
    if (l4.y > 0) acc += fmaxf(sqrtf(d1) - DELTA_VAR, 0.f);
    if (l4.z > 0) acc += fmaxf(sqrtf(d2) - DELTA_VAR, 0.f);
    if (l4.w > 0) acc += fmaxf(sqrtf(d3) - DELTA_VAR, 0.f);

    const float wsum = wave_sum(acc);
    if ((t & 63) == 0) wred[t >> 6] = wsum;
    __syncthreads();
    if (t == 0) ws[V_PART + blockIdx.x] = wred[0]+wred[1]+wred[2]+wred[3];
}

__global__ void k_final(const float* __restrict__ ws, float* __restrict__ out) {
    const int t = threadIdx.x;              // 256 thr; wave w <-> batch w
    __shared__ float vb[4];
    float s = 0.f;
    #pragma unroll
    for (int k = 0; k < 4; ++k) s += ws[V_PART + t*4 + k];
    s = wave_sum(s);
    if ((t & 63) == 0) vb[t >> 6] = s;
    __syncthreads();
    if (t == 0) {
        float tot = 0.f;
        for (int b = 0; b < NB; b++) {
            tot += ALPHA * (vb[b] / ws[T_NS+b])
                 + BETA * ws[T_DIST+b]
                 + GAMMA * ws[T_REG+b];
        }
        out[0] = tot * (1.f/NB);
    }
}

extern "C" void kernel_launch(void* const* d_in, const int* in_sizes, int n_in,
                              void* d_out, int out_size, void* d_ws, size_t ws_size,
                              hipStream_t stream) {
    const float* emb = (const float*)d_in[0];
    const int* lab = (const int*)d_in[1];
    float* out = (float*)d_out;
    float* ws = (float*)d_ws;

    k_hist<<<GRID_H, BLK_H, 0, stream>>>(emb, lab, ws);
    k_stats<<<NB, 256, 0, stream>>>(ws);
    k_var<<<GRID_V, BLK_V, 0, stream>>>(emb, lab, ws);
    k_final<<<1, 256, 0, stream>>>(ws, out);
}